// Round 1
// baseline (15924.507 us; speedup 1.0000x reference)
//
#include <hip/hip_runtime.h>
#include <hip/hip_fp16.h>
#include <math.h>

#define BB 512
#define HH 256
#define SS 168
#define TT 24
#define FIN 16
#define KC 32
#define TB 32
#define TU 32
#define XROW 288   // padded x0 row / padded dec_w_ih0 row (257 -> 288, zero-filled)

typedef unsigned long long ull;

__device__ __forceinline__ float sigf(float x) { return 1.f / (1.f + expf(-x)); }

// ---------------------------------------------------------------------------
// Fused LSTM step tile: gates = bias + X@Wih^T + Hprev@Whh^T, then pointwise.
// Block tile: 32 b x 32 u (=128 gate cols). 256 threads: bq=tid&7 (4 b each),
// ul=tid>>3 (1 u, 4 gates). Per kk: 2 x b128 LDS reads for 16 FMA.
// ---------------------------------------------------------------------------
__device__ __forceinline__ void lstm_tile(
    int b0, int u0,
    const float* __restrict__ X, int rsX, int KIN,
    const float* __restrict__ Wih, int rsWih,
    const float* __restrict__ Hprev,
    const float* __restrict__ Whh,
    const float* __restrict__ bias,
    float* __restrict__ C, float* __restrict__ Hout,
    __half* __restrict__ E16out, ull eStrideB,
    float (*Xs)[TB + 1], float (*Ws)[4 * TU + 4])
{
  const int tid = threadIdx.x;
  const int bq = tid & 7;    // b quad
  const int ul = tid >> 3;   // u local 0..31
  const int u = u0 + ul;

  float acc[4][4];
#pragma unroll
  for (int g = 0; g < 4; g++) {
    const float bv = bias[g * HH + u];
    acc[0][g] = bv; acc[1][g] = bv; acc[2][g] = bv; acc[3][g] = bv;
  }

#pragma unroll
  for (int ph = 0; ph < 2; ph++) {
    const float* A = ph ? Hprev : X;
    const float* W = ph ? Whh : Wih;
    const int rsA = ph ? HH : rsX;
    const int rsW = ph ? HH : rsWih;
    const int K = ph ? HH : KIN;
    for (int k0 = 0; k0 < K; k0 += KC) {
      const int kc = (KC < K - k0) ? KC : (K - k0);
      // ---- stage A tile (k-major, 32 kk x 32 b) ----
      if (kc == KC && (rsA & 3) == 0) {
        const int bi = tid & 31, kq = tid >> 5;          // kq 0..7
        const float4 v = *(const float4*)(A + (ull)(b0 + bi) * rsA + k0 + kq * 4);
        Xs[kq * 4 + 0][bi] = v.x; Xs[kq * 4 + 1][bi] = v.y;
        Xs[kq * 4 + 2][bi] = v.z; Xs[kq * 4 + 3][bi] = v.w;
      } else {
        for (int idx = tid; idx < kc * 32; idx += 256) {
          const int bi = idx & 31, kk = idx >> 5;
          Xs[kk][bi] = A[(ull)(b0 + bi) * rsA + k0 + kk];
        }
      }
      // ---- stage W tile (k-major, 32 kk x 128 cols; col = ul*4+gate) ----
      if (kc == KC && (rsW & 3) == 0) {
        const int cl = tid & 127, kq = tid >> 7;         // kq 0..1
        const int j = (cl & 3) * HH + u0 + (cl >> 2);
        const float* gw = W + (ull)j * rsW + k0 + kq * 16;
#pragma unroll
        for (int i = 0; i < 4; i++) {
          const float4 v = *(const float4*)(gw + i * 4);
          const int kk = kq * 16 + i * 4;
          Ws[kk + 0][cl] = v.x; Ws[kk + 1][cl] = v.y;
          Ws[kk + 2][cl] = v.z; Ws[kk + 3][cl] = v.w;
        }
      } else {
        for (int idx = tid; idx < kc * 128; idx += 256) {
          const int cl = idx & 127, kk = idx >> 7;
          const int j = (cl & 3) * HH + u0 + (cl >> 2);
          Ws[kk][cl] = W[(ull)j * rsW + k0 + kk];
        }
      }
      __syncthreads();
      // ---- compute ----
      if (kc == KC) {
#pragma unroll 8
        for (int kk = 0; kk < KC; kk++) {
          const float4 xv = *(const float4*)&Xs[kk][bq * 4];
          const float4 wv = *(const float4*)&Ws[kk][ul * 4];
          acc[0][0] += xv.x * wv.x; acc[0][1] += xv.x * wv.y; acc[0][2] += xv.x * wv.z; acc[0][3] += xv.x * wv.w;
          acc[1][0] += xv.y * wv.x; acc[1][1] += xv.y * wv.y; acc[1][2] += xv.y * wv.z; acc[1][3] += xv.y * wv.w;
          acc[2][0] += xv.z * wv.x; acc[2][1] += xv.z * wv.y; acc[2][2] += xv.z * wv.z; acc[2][3] += xv.z * wv.w;
          acc[3][0] += xv.w * wv.x; acc[3][1] += xv.w * wv.y; acc[3][2] += xv.w * wv.z; acc[3][3] += xv.w * wv.w;
        }
      } else {
        for (int kk = 0; kk < kc; kk++) {
          const float4 xv = *(const float4*)&Xs[kk][bq * 4];
          const float4 wv = *(const float4*)&Ws[kk][ul * 4];
          acc[0][0] += xv.x * wv.x; acc[0][1] += xv.x * wv.y; acc[0][2] += xv.x * wv.z; acc[0][3] += xv.x * wv.w;
          acc[1][0] += xv.y * wv.x; acc[1][1] += xv.y * wv.y; acc[1][2] += xv.y * wv.z; acc[1][3] += xv.y * wv.w;
          acc[2][0] += xv.z * wv.x; acc[2][1] += xv.z * wv.y; acc[2][2] += xv.z * wv.z; acc[2][3] += xv.z * wv.w;
          acc[3][0] += xv.w * wv.x; acc[3][1] += xv.w * wv.y; acc[3][2] += xv.w * wv.z; acc[3][3] += xv.w * wv.w;
        }
      }
      __syncthreads();
    }
  }
  // ---- pointwise epilogue: gate order i,f,g,o ----
#pragma unroll
  for (int bd = 0; bd < 4; bd++) {
    const int b = b0 + bq * 4 + bd;
    const float iv = sigf(acc[bd][0]);
    const float fv = sigf(acc[bd][1]);
    const float gv = tanhf(acc[bd][2]);
    const float ov = sigf(acc[bd][3]);
    const ull ci = (ull)b * HH + u;
    const float cn = fv * C[ci] + iv * gv;
    C[ci] = cn;
    const float hn = ov * tanhf(cn);
    Hout[ci] = hn;
    if (E16out) E16out[(ull)b * eStrideB + u] = __float2half(hn);
  }
}

// ---------------------------------------------------------------------------
// Encoder wavefront iteration t: blocks 0..127 do layer0 step t (t<168),
// blocks 128..255 do layer1 step t-1 (t>=1). Layer1 also emits fp16 enc_out.
// ---------------------------------------------------------------------------
__global__ __launch_bounds__(256, 2) void enc_step_kernel(
    const float* __restrict__ src,
    const float* __restrict__ wih0, const float* __restrict__ whh0, const float* __restrict__ bias0,
    const float* __restrict__ wih1, const float* __restrict__ whh1, const float* __restrict__ bias1,
    float* __restrict__ y0ring, float* __restrict__ h1buf,
    float* __restrict__ c0, float* __restrict__ c1,
    const float* __restrict__ zb, __half* __restrict__ E16, int t)
{
  __shared__ float Xs[KC][TB + 1];
  __shared__ float Ws[KC][4 * TU + 4];
  const int blk = blockIdx.x;
  if (blk < 128) {
    if (t >= SS) return;
    const int bt = blk & 15, ut = blk >> 4;
    const float* Hp = (t == 0) ? zb : (y0ring + (ull)((t - 1) & 1) * BB * HH);
    float* Ho = y0ring + (ull)(t & 1) * BB * HH;
    lstm_tile(bt * TB, ut * TU, src + t * FIN, SS * FIN, FIN, wih0, FIN,
              Hp, whh0, bias0, c0, Ho, nullptr, 0, Xs, Ws);
  } else {
    const int s = t - 1;
    if (s < 0) return;
    const int b2 = blk - 128;
    const int bt = b2 & 15, ut = b2 >> 4;
    const float* Hp = (s == 0) ? zb : (h1buf + (ull)((s - 1) & 1) * BB * HH);
    float* Ho = h1buf + (ull)(s & 1) * BB * HH;
    const float* Xp = y0ring + (ull)(s & 1) * BB * HH;
    lstm_tile(bt * TB, ut * TU, Xp, HH, HH, wih1, HH,
              Hp, whh1, bias1, c1, Ho, E16 + (ull)s * HH, (ull)SS * HH, Xs, Ws);
  }
}

// Standalone LSTM cell step (decoder). Grid: 128 blocks (16 b-tiles x 8 u-tiles).
__global__ __launch_bounds__(256, 2) void lstm_step_kernel(
    const float* __restrict__ X, int rsX, int KIN,
    const float* __restrict__ Wih, int rsWih,
    const float* __restrict__ Hprev, const float* __restrict__ Whh,
    const float* __restrict__ bias,
    float* __restrict__ C, float* __restrict__ Hout)
{
  __shared__ float Xs[KC][TB + 1];
  __shared__ float Ws[KC][4 * TU + 4];
  const int bt = blockIdx.x & 15, ut = blockIdx.x >> 4;
  lstm_tile(bt * TB, ut * TU, X, rsX, KIN, Wih, rsWih, Hprev, Whh, bias,
            C, Hout, nullptr, 0, Xs, Ws);
}

// ---------------------------------------------------------------------------
// Generic tiled gemm: C[m][n] = (bias?bias[n]:0) + sum_k A[m][k]*Bw[n][k]
// 64x64 tile, 256 threads, 4x4 per thread. K % 32 == 0, M,N % 64 == 0.
// ---------------------------------------------------------------------------
template <typename AT, typename CT>
__global__ __launch_bounds__(256, 2) void gemm_kernel(
    const AT* __restrict__ A, int rsA,
    const float* __restrict__ Bw, int rsB,
    const float* __restrict__ bias,
    CT* __restrict__ Cout, int rsC, int K)
{
  __shared__ float As[KC][65];
  __shared__ float Bs[KC][65];
  const int m0 = blockIdx.x * 64, n0 = blockIdx.y * 64;
  const int tid = threadIdx.x;
  const int mq = tid & 15, nq = tid >> 4;
  const int li = tid & 63, kq = tid >> 6;   // staging: 64 rows x 8 k each
  float acc[4][4] = {{0.f}};
  for (int k0 = 0; k0 < K; k0 += KC) {
    if constexpr (sizeof(AT) == 2) {
      float4 raw = *(const float4*)(A + (ull)(m0 + li) * rsA + k0 + kq * 8);
      const __half* hp = (const __half*)&raw;
#pragma unroll
      for (int i = 0; i < 8; i++) As[kq * 8 + i][li] = __half2float(hp[i]);
    } else {
      const float* ga = (const float*)A + (ull)(m0 + li) * rsA + k0 + kq * 8;
      const float4 v0 = *(const float4*)ga, v1 = *(const float4*)(ga + 4);
      As[kq * 8 + 0][li] = v0.x; As[kq * 8 + 1][li] = v0.y; As[kq * 8 + 2][li] = v0.z; As[kq * 8 + 3][li] = v0.w;
      As[kq * 8 + 4][li] = v1.x; As[kq * 8 + 5][li] = v1.y; As[kq * 8 + 6][li] = v1.z; As[kq * 8 + 7][li] = v1.w;
    }
    {
      const float* gb = Bw + (ull)(n0 + li) * rsB + k0 + kq * 8;
      const float4 v0 = *(const float4*)gb, v1 = *(const float4*)(gb + 4);
      Bs[kq * 8 + 0][li] = v0.x; Bs[kq * 8 + 1][li] = v0.y; Bs[kq * 8 + 2][li] = v0.z; Bs[kq * 8 + 3][li] = v0.w;
      Bs[kq * 8 + 4][li] = v1.x; Bs[kq * 8 + 5][li] = v1.y; Bs[kq * 8 + 6][li] = v1.z; Bs[kq * 8 + 7][li] = v1.w;
    }
    __syncthreads();
#pragma unroll 8
    for (int kk = 0; kk < KC; kk++) {
      const float4 a4 = *(const float4*)&As[kk][mq * 4];
      const float4 b4 = *(const float4*)&Bs[kk][nq * 4];
      acc[0][0] += a4.x * b4.x; acc[0][1] += a4.x * b4.y; acc[0][2] += a4.x * b4.z; acc[0][3] += a4.x * b4.w;
      acc[1][0] += a4.y * b4.x; acc[1][1] += a4.y * b4.y; acc[1][2] += a4.y * b4.z; acc[1][3] += a4.y * b4.w;
      acc[2][0] += a4.z * b4.x; acc[2][1] += a4.z * b4.y; acc[2][2] += a4.z * b4.z; acc[2][3] += a4.z * b4.w;
      acc[3][0] += a4.w * b4.x; acc[3][1] += a4.w * b4.y; acc[3][2] += a4.w * b4.z; acc[3][3] += a4.w * b4.w;
    }
    __syncthreads();
  }
#pragma unroll
  for (int i = 0; i < 4; i++) {
    const int m = m0 + mq * 4 + i;
    float r[4];
#pragma unroll
    for (int j = 0; j < 4; j++) r[j] = acc[i][j] + (bias ? bias[n0 + nq * 4 + j] : 0.f);
    if constexpr (sizeof(CT) == 2) {
      __half2* p = (__half2*)((__half*)Cout + (ull)m * rsC + n0 + nq * 4);
      __half2 h0; h0.x = __float2half(r[0]); h0.y = __float2half(r[1]);
      __half2 h1; h1.x = __float2half(r[2]); h1.y = __float2half(r[3]);
      p[0] = h0; p[1] = h1;
    } else {
      float4 v; v.x = r[0]; v.y = r[1]; v.z = r[2]; v.w = r[3];
      *(float4*)((float*)Cout + (ull)m * rsC + n0 + nq * 4) = v;
    }
  }
}

// ---------------------------------------------------------------------------
// Attention for one decoder step. Block = one batch row b.
// scores[s] = sum_g v[g]*tanh(P16[b,s,g] + q[b,g]); softmax over s; ctx into
// x0[b][1..256]. (pos_bias omitted: uniform-over-s shift, softmax-invariant.)
// ---------------------------------------------------------------------------
__global__ __launch_bounds__(256) void attn_kernel(
    const float* __restrict__ q, const __half* __restrict__ P16,
    const __half* __restrict__ E16, const float* __restrict__ attn_v,
    float* __restrict__ x0)
{
  const int b = blockIdx.x;
  const int tid = threadIdx.x;
  __shared__ float qs[256], vs[256], sc[168], ctxs[512], sred[2];
  qs[tid] = q[b * HH + tid];
  vs[tid] = attn_v[tid];
  __syncthreads();
  const int wv = tid >> 6, lane = tid & 63;
  for (int s = wv; s < SS; s += 4) {
    const __half2* Pr = (const __half2*)(P16 + ((ull)b * SS + s) * HH);
    float a = 0.f;
#pragma unroll
    for (int jj = 0; jj < 2; jj++) {
      const int i2 = lane + 64 * jj;
      const float2 pv = __half22float2(Pr[i2]);
      const int g0 = i2 * 2;
      a += vs[g0] * tanhf(pv.x + qs[g0]);
      a += vs[g0 + 1] * tanhf(pv.y + qs[g0 + 1]);
    }
#pragma unroll
    for (int m = 32; m >= 1; m >>= 1) a += __shfl_xor(a, m, 64);
    if (lane == 0) sc[s] = a;
  }
  __syncthreads();
  if (tid < 64) {
    float m = -1e30f;
    for (int i = tid; i < SS; i += 64) m = fmaxf(m, sc[i]);
#pragma unroll
    for (int mm = 32; mm >= 1; mm >>= 1) m = fmaxf(m, __shfl_xor(m, mm, 64));
    if (tid == 0) sred[0] = m;
  }
  __syncthreads();
  const float smax = sred[0];
  if (tid < SS) sc[tid] = expf(sc[tid] - smax);
  __syncthreads();
  if (tid < 64) {
    float ssum = 0.f;
    for (int i = tid; i < SS; i += 64) ssum += sc[i];
#pragma unroll
    for (int mm = 32; mm >= 1; mm >>= 1) ssum += __shfl_xor(ssum, mm, 64);
    if (tid == 0) sred[1] = ssum;
  }
  __syncthreads();
  const float rinv = 1.f / sred[1];
  const int u2 = tid & 127, sh = tid >> 7;
  float cx = 0.f, cy = 0.f;
  for (int s = sh * 84; s < sh * 84 + 84; s++) {
    const float w = sc[s] * rinv;
    const float2 ev = __half22float2(*(const __half2*)(E16 + ((ull)b * SS + s) * HH + u2 * 2));
    cx += w * ev.x; cy += w * ev.y;
  }
  ctxs[sh * 256 + u2 * 2] = cx;
  ctxs[sh * 256 + u2 * 2 + 1] = cy;
  __syncthreads();
  x0[(ull)b * XROW + 1 + tid] = ctxs[tid] + ctxs[256 + tid];
}

// pred = h1 @ fc_w + fc_b -> out[b*T + t] and x0[b][0] (next dec_in).
__global__ __launch_bounds__(256) void fc_kernel(
    const float* __restrict__ h1, const float* __restrict__ fc_w,
    const float* __restrict__ fc_b, float* __restrict__ out,
    float* __restrict__ x0, int t)
{
  const int gid = blockIdx.x * 256 + threadIdx.x;
  const int b = gid >> 6, lane = gid & 63;
  float a = 0.f;
#pragma unroll
  for (int j = 0; j < 4; j++) a += h1[(ull)b * HH + lane + 64 * j] * fc_w[lane + 64 * j];
#pragma unroll
  for (int m = 32; m >= 1; m >>= 1) a += __shfl_xor(a, m, 64);
  if (lane == 0) {
    const float p = a + fc_b[0];
    out[(ull)b * TT + t] = p;
    x0[(ull)b * XROW] = p;
  }
}

// Zero zb/c0/c1, set x0 col0 = src[:, -1, -1], zero x0 pad cols 257..287.
__global__ void init_kernel(const float* __restrict__ src, float* __restrict__ zr,
                            float* __restrict__ x0)
{
  const int i = blockIdx.x * 256 + threadIdx.x;
  if (i < 3 * BB * HH) zr[i] = 0.f;
  if (i < BB) x0[(ull)i * XROW] = src[(ull)i * SS * FIN + (SS - 1) * FIN + (FIN - 1)];
  const int npad = XROW - 1 - HH;  // 31
  if (i < BB * npad) {
    const int b = i / npad;
    const int c = 1 + HH + (i - b * npad);
    x0[(ull)b * XROW + c] = 0.f;
  }
}

// Pad dec_w_ih0 (1024 x 257) into (1024 x 288) zero-filled for aligned loads.
__global__ void wpad_kernel(const float* __restrict__ w, float* __restrict__ wp)
{
  const int i = blockIdx.x * 256 + threadIdx.x;
  if (i >= 1024 * XROW) return;
  const int j = i / XROW, k = i - j * XROW;
  wp[i] = (k < HH + 1) ? w[(ull)j * (HH + 1) + k] : 0.f;
}

extern "C" void kernel_launch(void* const* d_in, const int* in_sizes, int n_in,
                              void* d_out, int out_size, void* d_ws, size_t ws_size,
                              hipStream_t stream)
{
  const float* src    = (const float*)d_in[0];
  const float* ewih0  = (const float*)d_in[1];
  const float* ewhh0  = (const float*)d_in[2];
  const float* eb0    = (const float*)d_in[3];
  const float* ewih1  = (const float*)d_in[4];
  const float* ewhh1  = (const float*)d_in[5];
  const float* eb1    = (const float*)d_in[6];
  const float* dwih0  = (const float*)d_in[7];
  const float* dwhh0  = (const float*)d_in[8];
  const float* db0    = (const float*)d_in[9];
  const float* dwih1  = (const float*)d_in[10];
  const float* dwhh1  = (const float*)d_in[11];
  const float* db1    = (const float*)d_in[12];
  const float* attn_w = (const float*)d_in[13];
  const float* attn_b = (const float*)d_in[14];
  const float* attn_v = (const float*)d_in[15];
  // d_in[16] pos_bias: added post-tanh uniformly over s -> softmax-invariant, unused.
  const float* fc_w   = (const float*)d_in[17];
  const float* fc_b   = (const float*)d_in[18];
  float* out = (float*)d_out;

  float* f0 = (float*)d_ws;
  const ull BH = (ull)BB * HH;
  float* zb     = f0;                 // zero h for step 0           (BH)
  float* c0     = f0 + BH;            // layer0 / dec cell0 c state  (BH)
  float* c1     = f0 + 2 * BH;        // layer1 / dec cell1 c state  (BH)
  float* y0ring = f0 + 3 * BH;        // layer0 h ring, 2 slots      (2 BH)
  float* h1buf  = f0 + 5 * BH;        // layer1 / dec cell1 h ping-pong (2 BH)
  float* h0buf  = f0 + 7 * BH;        // dec cell0 h ping-pong       (2 BH)
  float* q      = f0 + 9 * BH;        // h1 @ Wd^T + attn_b          (BH)
  float* x0     = f0 + 10 * BH;       // [dec_in | ctx | 0-pad]      (512*288)
  float* wpad   = x0 + (ull)BB * XROW;        // padded dec_w_ih0 (1024*288)
  __half* E16   = (__half*)(wpad + (ull)1024 * XROW);  // enc_out fp16 (B,S,H)
  __half* P16   = E16 + (ull)BB * SS * HH;             // enc_proj fp16 (B,S,H)

  init_kernel<<<1536, 256, 0, stream>>>(src, f0, x0);
  wpad_kernel<<<1152, 256, 0, stream>>>(dwih0, wpad);

  // Encoder: diagonal wavefront, layer0[t] + layer1[t-1] per launch.
  for (int t = 0; t <= SS; t++)
    enc_step_kernel<<<256, 256, 0, stream>>>(src, ewih0, ewhh0, eb0, ewih1, ewhh1, eb1,
                                             y0ring, h1buf, c0, c1, zb, E16, t);

  // enc_proj = enc_out @ We^T (We = attn_w[:, :H]), fp16 in/out, fp32 accum.
  gemm_kernel<__half, __half><<<dim3(BB * SS / 64, HH / 64), 256, 0, stream>>>(
      E16, HH, attn_w, 2 * HH, nullptr, P16, HH, HH);

  // Decoder.
  for (int t = 0; t < TT; t++) {
    const float* h1in = h1buf + (ull)((t + 1) & 1) * BH;   // t=0 -> slot1 = enc final
    const float* h0in = (t == 0) ? (y0ring + BH) : (h0buf + (ull)((t + 1) & 1) * BH);
    float* h0out = h0buf + (ull)(t & 1) * BH;
    float* h1out = h1buf + (ull)(t & 1) * BH;
    // q = h1 @ Wd^T + attn_b  (Wd = attn_w[:, H:])
    gemm_kernel<float, float><<<dim3(BB / 64, HH / 64), 256, 0, stream>>>(
        h1in, HH, attn_w + HH, 2 * HH, attn_b, q, HH, HH);
    attn_kernel<<<BB, 256, 0, stream>>>(q, P16, E16, attn_v, x0);
    // cell0: x = [dec_in, ctx] (padded to 288)
    lstm_step_kernel<<<128, 256, 0, stream>>>(x0, XROW, XROW, wpad, XROW,
                                              h0in, dwhh0, db0, c0, h0out);
    // cell1: x = h0_new
    lstm_step_kernel<<<128, 256, 0, stream>>>(h0out, HH, HH, dwih1, HH,
                                              h1in, dwhh1, db1, c1, h1out);
    fc_kernel<<<128, 256, 0, stream>>>(h1out, fc_w, fc_b, out, x0, t);
  }
}